// Round 2
// baseline (567.204 us; speedup 1.0000x reference)
//
#include <hip/hip_runtime.h>

// Problem constants (match reference setup_inputs).
constexpr int B = 32;
constexpr int N = 8732;
constexpr int G = 100;      // gt boxes per batch
constexpr float TH = 0.5f;  // reference hard-codes th = 0.5

constexpr int BLK = 256;
constexpr int BLOCKS_PER_B = (N + BLK - 1) / BLK;  // 35

__global__ __launch_bounds__(BLK) void iou_masks_kernel(
    const float4* __restrict__ boxes,   // [B][N] cx,cy,w,h
    const float4* __restrict__ gt,      // [B][G] cx,cy,w,h
    const int*    __restrict__ nobj,    // [B]
    float*        __restrict__ out)     // [3][B][N][G]: ious, pos, neg
{
    // Bitwise-match the numpy fp32 reference: no FMA contraction.
    // (union = (area_p + area_g) - inter etc. must round each op separately;
    //  -ffp-contract=fast would fuse mul into add/sub and flip iou>0.5 bits.)
    #pragma clang fp contract(off)

    __shared__ float gx1[G], gy1[G], gx2[G], gy2[G], gar[G];

    const int b = blockIdx.x / BLOCKS_PER_B;
    const int i = (blockIdx.x % BLOCKS_PER_B) * BLK + threadIdx.x;

    // Stage this batch's GT boxes into LDS as xyxy + area.
    if (threadIdx.x < G) {
        float4 g = gt[b * G + threadIdx.x];
        float hw = g.z * 0.5f, hh = g.w * 0.5f;   // *0.5 is exact
        float x1 = g.x - hw, y1 = g.y - hh;
        float x2 = g.x + hw, y2 = g.y + hh;
        gx1[threadIdx.x] = x1; gy1[threadIdx.x] = y1;
        gx2[threadIdx.x] = x2; gy2[threadIdx.x] = y2;
        gar[threadIdx.x] = (x2 - x1) * (y2 - y1);
    }
    __syncthreads();

    if (i >= N) return;

    const int nv = nobj[b];

    float4 p = boxes[(size_t)b * N + i];
    float hw = p.z * 0.5f, hh = p.w * 0.5f;
    const float px1 = p.x - hw, py1 = p.y - hh;
    const float px2 = p.x + hw, py2 = p.y + hh;
    const float par = (px2 - px1) * (py2 - py1);

    const size_t rowOff = ((size_t)b * N + i) * (size_t)G;     // multiple of 4
    const size_t stride = (size_t)B * N * G;                   // multiple of 4
    float4* __restrict__ iou_o = (float4*)(out + rowOff);
    float4* __restrict__ pos_o = (float4*)(out + stride + rowOff);
    float4* __restrict__ neg_o = (float4*)(out + 2 * stride + rowOff);

    #pragma unroll 5
    for (int jq = 0; jq < G / 4; ++jq) {
        float iou[4], pos[4], neg[4];
        #pragma unroll
        for (int k = 0; k < 4; ++k) {
            const int j = jq * 4 + k;
            const float ix1 = fmaxf(px1, gx1[j]);
            const float iy1 = fmaxf(py1, gy1[j]);
            const float ix2 = fminf(px2, gx2[j]);
            const float iy2 = fminf(py2, gy2[j]);
            const float iw = fmaxf(ix2 - ix1, 0.0f);
            const float ih = fmaxf(iy2 - iy1, 0.0f);
            const float inter = iw * ih;                 // separate rounding
            const float uni = (par + gar[j]) - inter;    // separate roundings
            float v = inter / uni;                       // IEEE div
            const bool valid = j < nv;
            v = valid ? v : 0.0f;
            iou[k] = v;
            pos[k] = (valid && v > TH) ? 1.0f : 0.0f;
            neg[k] = (valid && v < TH) ? 1.0f : 0.0f;
        }
        iou_o[jq] = make_float4(iou[0], iou[1], iou[2], iou[3]);
        pos_o[jq] = make_float4(pos[0], pos[1], pos[2], pos[3]);
        neg_o[jq] = make_float4(neg[0], neg[1], neg[2], neg[3]);
    }
}

extern "C" void kernel_launch(void* const* d_in, const int* in_sizes, int n_in,
                              void* d_out, int out_size, void* d_ws, size_t ws_size,
                              hipStream_t stream) {
    // d_in order: [0] threshhold (int,1) [1] batch_boxes (B*N*4 f32)
    //             [2] batch_classes (B*N i32, unused) [3] batch_gt (B*G*4 f32)
    //             [4] batch_num_objects (B i32)
    const float4* boxes = (const float4*)d_in[1];
    const float4* gt    = (const float4*)d_in[3];
    const int*    nobj  = (const int*)d_in[4];
    float*        out   = (float*)d_out;

    dim3 grid(B * BLOCKS_PER_B);
    dim3 block(BLK);
    iou_masks_kernel<<<grid, block, 0, stream>>>(boxes, gt, nobj, out);
}

// Round 4
// 355.220 us; speedup vs baseline: 1.5968x; 1.5968x over previous
//
#include <hip/hip_runtime.h>

// Problem constants (match reference setup_inputs).
constexpr int B = 32;
constexpr int N = 8732;
constexpr int G = 100;      // gt boxes per batch
constexpr float TH = 0.5f;  // reference hard-codes th = 0.5

constexpr int BLK  = 256;
constexpr int ROWS = 256;                              // pred rows per block
constexpr int BLOCKS_PER_B = (N + ROWS - 1) / ROWS;    // 35
constexpr int QPR = G / 4;                             // float4s per row = 25

__global__ __launch_bounds__(BLK) void iou_masks_kernel(
    const float4* __restrict__ boxes,   // [B][N] cx,cy,w,h
    const float4* __restrict__ gt,      // [B][G] cx,cy,w,h
    const int*    __restrict__ nobj,    // [B]
    float*        __restrict__ out)     // [3][B][N][G]: ious, pos, neg
{
    // Bitwise-match the numpy fp32 reference: no FMA contraction.
    #pragma clang fp contract(off)

    __shared__ float4 sgt[G];           // gt xyxy
    __shared__ float  sgar[G];          // gt area
    __shared__ float  sp1x[ROWS], sp1y[ROWS], sp2x[ROWS], sp2y[ROWS], spar[ROWS];

    const int b  = blockIdx.x / BLOCKS_PER_B;
    const int i0 = (blockIdx.x % BLOCKS_PER_B) * ROWS;
    const int nrows = min(ROWS, N - i0);
    const int t  = threadIdx.x;

    if (t < G) {
        float4 g = gt[b * G + t];
        float hw = g.z * 0.5f, hh = g.w * 0.5f;   // *0.5 exact
        float x1 = g.x - hw, y1 = g.y - hh;
        float x2 = g.x + hw, y2 = g.y + hh;
        sgt[t]  = make_float4(x1, y1, x2, y2);
        sgar[t] = (x2 - x1) * (y2 - y1);
    }
    if (t < nrows) {
        float4 p = boxes[(size_t)b * N + i0 + t];
        float hw = p.z * 0.5f, hh = p.w * 0.5f;
        float x1 = p.x - hw, y1 = p.y - hh;
        float x2 = p.x + hw, y2 = p.y + hh;
        sp1x[t] = x1; sp1y[t] = y1; sp2x[t] = x2; sp2y[t] = y2;
        spar[t] = (x2 - x1) * (y2 - y1);
    }
    __syncthreads();

    const int nv = nobj[b];
    const int nq = nrows * QPR;                         // float4s per array
    const size_t base4   = ((size_t)b * N + i0) * QPR;  // chunk start (float4 units)
    const size_t stride4 = (size_t)B * N * QPR;         // array stride (float4 units)
    float4* __restrict__ o = (float4*)out;

    // Fully-coalesced writes: consecutive threads write consecutive float4s.
    for (int pos4 = t; pos4 < nq; pos4 += BLK) {
        const int il = pos4 / QPR;          // local pred row
        const int jq = pos4 - il * QPR;     // float4 index within row
        const float p1x = sp1x[il], p1y = sp1y[il];
        const float p2x = sp2x[il], p2y = sp2y[il];
        const float par = spar[il];

        float iou[4], pos[4], neg[4];
        #pragma unroll
        for (int c = 0; c < 4; ++c) {
            const int j = jq * 4 + c;
            const float4 g = sgt[j];
            const float ix1 = fmaxf(p1x, g.x);
            const float iy1 = fmaxf(p1y, g.y);
            const float ix2 = fminf(p2x, g.z);
            const float iy2 = fminf(p2y, g.w);
            const float iw = fmaxf(ix2 - ix1, 0.0f);
            const float ih = fmaxf(iy2 - iy1, 0.0f);
            const float inter = iw * ih;                // separate rounding
            const float uni = (par + sgar[j]) - inter;  // separate roundings
            float v = inter / uni;                      // IEEE div
            const bool valid = j < nv;
            v = valid ? v : 0.0f;
            iou[c] = v;
            pos[c] = (valid && v > TH) ? 1.0f : 0.0f;
            neg[c] = (valid && v < TH) ? 1.0f : 0.0f;
        }
        o[base4 + pos4]               = make_float4(iou[0], iou[1], iou[2], iou[3]);
        o[stride4 + base4 + pos4]     = make_float4(pos[0], pos[1], pos[2], pos[3]);
        o[2 * stride4 + base4 + pos4] = make_float4(neg[0], neg[1], neg[2], neg[3]);
    }
}

extern "C" void kernel_launch(void* const* d_in, const int* in_sizes, int n_in,
                              void* d_out, int out_size, void* d_ws, size_t ws_size,
                              hipStream_t stream) {
    // d_in order: [0] threshhold (int,1) [1] batch_boxes (B*N*4 f32)
    //             [2] batch_classes (B*N i32, unused) [3] batch_gt (B*G*4 f32)
    //             [4] batch_num_objects (B i32)
    const float4* boxes = (const float4*)d_in[1];
    const float4* gt    = (const float4*)d_in[3];
    const int*    nobj  = (const int*)d_in[4];
    float*        out   = (float*)d_out;

    dim3 grid(B * BLOCKS_PER_B);
    dim3 block(BLK);
    iou_masks_kernel<<<grid, block, 0, stream>>>(boxes, gt, nobj, out);
}

// Round 8
// 350.050 us; speedup vs baseline: 1.6204x; 1.0148x over previous
//
#include <hip/hip_runtime.h>

// Problem constants (match reference setup_inputs).
constexpr int B = 32;
constexpr int N = 8732;
constexpr int G = 100;      // gt boxes per batch
constexpr float TH = 0.5f;  // reference hard-codes th = 0.5

constexpr int BLK  = 256;
constexpr int ROWS = 256;                              // pred rows per block
constexpr int BLOCKS_PER_B = (N + ROWS - 1) / ROWS;    // 35
constexpr int QPR = G / 4;                             // float4s per row = 25

// Native clang vector: __builtin_nontemporal_store needs a real vector type,
// not HIP's struct-based float4.
typedef float f32x4 __attribute__((ext_vector_type(4)));

__global__ __launch_bounds__(BLK) void iou_masks_kernel(
    const float4* __restrict__ boxes,   // [B][N] cx,cy,w,h
    const float4* __restrict__ gt,      // [B][G] cx,cy,w,h
    const int*    __restrict__ nobj,    // [B]
    float*        __restrict__ out)     // [3][B][N][G]: ious, pos, neg
{
    // Bitwise-match the numpy fp32 reference: no FMA contraction.
    #pragma clang fp contract(off)

    __shared__ float4 sgt[G];           // gt xyxy
    __shared__ float  sgar[G];          // gt area
    __shared__ float  sp1x[ROWS], sp1y[ROWS], sp2x[ROWS], sp2y[ROWS], spar[ROWS];

    const int b  = blockIdx.x / BLOCKS_PER_B;
    const int i0 = (blockIdx.x % BLOCKS_PER_B) * ROWS;
    const int nrows = min(ROWS, N - i0);
    const int t  = threadIdx.x;

    if (t < G) {
        float4 g = gt[b * G + t];
        float hw = g.z * 0.5f, hh = g.w * 0.5f;   // *0.5 exact
        float x1 = g.x - hw, y1 = g.y - hh;
        float x2 = g.x + hw, y2 = g.y + hh;
        sgt[t]  = make_float4(x1, y1, x2, y2);
        sgar[t] = (x2 - x1) * (y2 - y1);
    }
    if (t < nrows) {
        float4 p = boxes[(size_t)b * N + i0 + t];
        float hw = p.z * 0.5f, hh = p.w * 0.5f;
        float x1 = p.x - hw, y1 = p.y - hh;
        float x2 = p.x + hw, y2 = p.y + hh;
        sp1x[t] = x1; sp1y[t] = y1; sp2x[t] = x2; sp2y[t] = y2;
        spar[t] = (x2 - x1) * (y2 - y1);
    }
    __syncthreads();

    const int nv = nobj[b];
    const int nq = nrows * QPR;                         // float4s per array
    const size_t base4   = ((size_t)b * N + i0) * QPR;  // chunk start (float4 units)
    const size_t stride4 = (size_t)B * N * QPR;         // array stride (float4 units)
    f32x4* __restrict__ o = (f32x4*)out;

    // Fully-coalesced streaming writes: consecutive threads write consecutive
    // float4s; nontemporal hint (nt) since nothing ever re-reads these lines.
    for (int pos4 = t; pos4 < nq; pos4 += BLK) {
        const int il = pos4 / QPR;          // local pred row
        const int jq = pos4 - il * QPR;     // float4 index within row
        const float p1x = sp1x[il], p1y = sp1y[il];
        const float p2x = sp2x[il], p2y = sp2y[il];
        const float par = spar[il];

        f32x4 iou, pos, neg;
        #pragma unroll
        for (int c = 0; c < 4; ++c) {
            const int j = jq * 4 + c;
            const float4 g = sgt[j];
            const float ix1 = fmaxf(p1x, g.x);
            const float iy1 = fmaxf(p1y, g.y);
            const float ix2 = fminf(p2x, g.z);
            const float iy2 = fminf(p2y, g.w);
            const float iw = fmaxf(ix2 - ix1, 0.0f);
            const float ih = fmaxf(iy2 - iy1, 0.0f);
            const float inter = iw * ih;                // separate rounding
            const float uni = (par + sgar[j]) - inter;  // separate roundings
            float v = inter / uni;                      // IEEE div
            const bool valid = j < nv;
            v = valid ? v : 0.0f;
            iou[c] = v;
            pos[c] = (valid && v > TH) ? 1.0f : 0.0f;
            neg[c] = (valid && v < TH) ? 1.0f : 0.0f;
        }
        __builtin_nontemporal_store(iou, &o[base4 + pos4]);
        __builtin_nontemporal_store(pos, &o[stride4 + base4 + pos4]);
        __builtin_nontemporal_store(neg, &o[2 * stride4 + base4 + pos4]);
    }
}

extern "C" void kernel_launch(void* const* d_in, const int* in_sizes, int n_in,
                              void* d_out, int out_size, void* d_ws, size_t ws_size,
                              hipStream_t stream) {
    // d_in order: [0] threshhold (int,1) [1] batch_boxes (B*N*4 f32)
    //             [2] batch_classes (B*N i32, unused) [3] batch_gt (B*G*4 f32)
    //             [4] batch_num_objects (B i32)
    const float4* boxes = (const float4*)d_in[1];
    const float4* gt    = (const float4*)d_in[3];
    const int*    nobj  = (const int*)d_in[4];
    float*        out   = (float*)d_out;

    dim3 grid(B * BLOCKS_PER_B);
    dim3 block(BLK);
    iou_masks_kernel<<<grid, block, 0, stream>>>(boxes, gt, nobj, out);
}